// Round 1
// baseline (879.997 us; speedup 1.0000x reference)
//
#include <hip/hip_runtime.h>
#include <math.h>

#define T_TOKENS 16384
#define HID      4096
#define NEXP     256
#define NGROUP   8
#define GSIZE    32
#define TOPKG    4
#define TOPK     8
#define RSCALE   2.5f

#define BT   32           // tokens per block
#define KT   32           // k-tile
#define ASTR 36           // As row stride (32 + pad)
#define BSTR 288          // Bs physical row stride (256 + 4*(e>>5) swizzle, max 283)
#define LSTR (NEXP + 1)   // logits row stride (bank-conflict-free per-token scans)

// One block: 32 tokens x all 256 experts, K=4096 in 128 tiles of 32.
// After GEMM, logits -> LDS (aliasing the staging buffers), sigmoid, then
// per-token serial routing on threads 0..31.
__global__ __launch_bounds__(256, 2)
void router_fused_f32(const float* __restrict__ hs,
                      const float* __restrict__ wt,
                      const float* __restrict__ bias,
                      float* __restrict__ out)
{
    // staging: As[KT][ASTR] + Bs[KT][BSTR] = 1152 + 9216 floats = 41.5 KB
    // logits:  Lg[BT][LSTR] = 8224 floats (aliases smem after GEMM)
    __shared__ float smem[KT * ASTR + KT * BSTR];
    __shared__ float bias_s[NEXP];

    float* As = smem;
    float* Bs = smem + KT * ASTR;
    float* Lg = smem;

    const int tid = threadIdx.x;
    const int t0  = blockIdx.x * BT;

    bias_s[tid] = bias[tid];

    // compute mapping: 16 tx (expert dir, 16 experts each) x 16 ty (token dir, 2 tokens each)
    const int tx = tid & 15;
    const int ty = tid >> 4;
    // physical base col in Bs for e0 = tx*16 (swizzle: colphys = e + 4*(e>>5))
    const int bb = tx * 16 + 4 * (tx >> 1);

    float acc[2][16];
#pragma unroll
    for (int i = 0; i < 2; ++i)
#pragma unroll
        for (int j = 0; j < 16; ++j) acc[i][j] = 0.0f;

    for (int k0 = 0; k0 < HID; k0 += KT) {
        __syncthreads();
        // ---- stage A: 32 rows x 8 float4 = 256 slots, 1 per thread, stored transposed As[k][t]
        {
            const int row = tid >> 3, c4 = tid & 7;
            const float4 v = *reinterpret_cast<const float4*>(
                hs + (size_t)(t0 + row) * HID + k0 + c4 * 4);
            As[(c4 * 4 + 0) * ASTR + row] = v.x;
            As[(c4 * 4 + 1) * ASTR + row] = v.y;
            As[(c4 * 4 + 2) * ASTR + row] = v.z;
            As[(c4 * 4 + 3) * ASTR + row] = v.w;
        }
        // ---- stage B: 256 rows x 8 float4 = 2048 slots, 8 per thread, transposed+swizzled Bs[k][colphys(e)]
#pragma unroll
        for (int s = 0; s < 8; ++s) {
            const int slot = tid + s * 256;
            const int row = slot >> 3, c4 = slot & 7;
            const float4 v = *reinterpret_cast<const float4*>(
                wt + (size_t)row * HID + k0 + c4 * 4);
            const int cp = row + 4 * (row >> 5);
            Bs[(c4 * 4 + 0) * BSTR + cp] = v.x;
            Bs[(c4 * 4 + 1) * BSTR + cp] = v.y;
            Bs[(c4 * 4 + 2) * BSTR + cp] = v.z;
            Bs[(c4 * 4 + 3) * BSTR + cp] = v.w;
        }
        __syncthreads();
        // ---- compute: per k, a[2] broadcast + b[16] (2-way bank alias = free)
#pragma unroll 8
        for (int k = 0; k < KT; ++k) {
            const float2 av = *reinterpret_cast<const float2*>(&As[k * ASTR + ty * 2]);
            const float4 b0 = *reinterpret_cast<const float4*>(&Bs[k * BSTR + bb]);
            const float4 b1 = *reinterpret_cast<const float4*>(&Bs[k * BSTR + bb + 4]);
            const float4 b2 = *reinterpret_cast<const float4*>(&Bs[k * BSTR + bb + 8]);
            const float4 b3 = *reinterpret_cast<const float4*>(&Bs[k * BSTR + bb + 12]);
            const float b[16] = {b0.x, b0.y, b0.z, b0.w, b1.x, b1.y, b1.z, b1.w,
                                 b2.x, b2.y, b2.z, b2.w, b3.x, b3.y, b3.z, b3.w};
            const float a0 = av.x, a1 = av.y;
#pragma unroll
            for (int j = 0; j < 16; ++j) {
                acc[0][j] = fmaf(a0, b[j], acc[0][j]);
                acc[1][j] = fmaf(a1, b[j], acc[1][j]);
            }
        }
    }

    // ---- dump logits to LDS (aliases staging; all reads of As/Bs are done)
    __syncthreads();
#pragma unroll
    for (int i = 0; i < 2; ++i)
#pragma unroll
        for (int j = 0; j < 16; ++j)
            Lg[(ty * 2 + i) * LSTR + tx * 16 + j] = acc[i][j];
    __syncthreads();

    // ---- sigmoid pass: 256 threads x 32 rows, col = tid (conflict-free)
#pragma unroll
    for (int s = 0; s < BT; ++s) {
        const float x = Lg[s * LSTR + tid];
        Lg[s * LSTR + tid] = 1.0f / (1.0f + expf(-x));
    }
    __syncthreads();

    // ---- routing: one thread per token (threads 0..31)
    if (tid < BT) {
        const float* row = &Lg[tid * LSTR];   // sigmoid scores; +tid stagger -> 2 lanes/bank

        // group scores: sum of top-2 of (score + bias) per group of 32
        float gs[NGROUP];
#pragma unroll
        for (int g = 0; g < NGROUP; ++g) {
            float m1 = -1e30f, m2 = -1e30f;
            for (int i = 0; i < GSIZE; ++i) {
                const int e = g * GSIZE + i;
                const float v = row[e] + bias_s[e];
                if (v > m1) { m2 = m1; m1 = v; }
                else if (v > m2) { m2 = v; }
            }
            gs[g] = m1 + m2;
        }

        // top-4 groups (strict >, lower index wins ties — matches lax.top_k)
        unsigned gmask = 0;
#pragma unroll
        for (int r = 0; r < TOPKG; ++r) {
            int bi = 0; float bv = -1e30f;
#pragma unroll
            for (int g = 0; g < NGROUP; ++g) {
                const bool taken = (gmask >> g) & 1;
                if (!taken && gs[g] > bv) { bv = gs[g]; bi = g; }
            }
            gmask |= 1u << bi;
        }

        // top-8 over masked array (disallowed -> 0.0, exactly like reference),
        // stable insertion (strict >) keeps lower-index-first ordering for ties
        float val[TOPK]; int id[TOPK];
#pragma unroll
        for (int r = 0; r < TOPK; ++r) { val[r] = -1e30f; id[r] = 0; }
        for (int e = 0; e < NEXP; ++e) {
            const bool allowed = (gmask >> (e >> 5)) & 1;
            const float v = allowed ? (row[e] + bias_s[e]) : 0.0f;
            if (v > val[TOPK - 1]) {
#pragma unroll
                for (int p = TOPK - 1; p >= 1; --p) {
                    if (v > val[p - 1])      { val[p] = val[p - 1]; id[p] = id[p - 1]; }
                    else if (v > val[p])     { val[p] = v;          id[p] = e; }
                }
                if (v > val[0]) { val[0] = v; id[0] = e; }
            }
        }

        // weights: pure sigmoid scores at chosen indices, normalized, scaled
        float w[TOPK]; float sum = 0.0f;
#pragma unroll
        for (int r = 0; r < TOPK; ++r) { w[r] = row[id[r]]; sum += w[r]; }
        const float inv = RSCALE / (sum + 1e-20f);

        const size_t t = (size_t)(t0 + tid);
#pragma unroll
        for (int r = 0; r < TOPK; ++r) {
            out[t * TOPK + r] = (float)id[r];                          // indices (as float)
            out[(size_t)T_TOKENS * TOPK + t * TOPK + r] = w[r] * inv;  // weights
        }
    }
}

extern "C" void kernel_launch(void* const* d_in, const int* in_sizes, int n_in,
                              void* d_out, int out_size, void* d_ws, size_t ws_size,
                              hipStream_t stream) {
    const float* hs   = (const float*)d_in[0];   // hidden_states [16384, 4096] f32
    const float* wt   = (const float*)d_in[1];   // weight        [256, 4096]   f32
    const float* bias = (const float*)d_in[2];   // e_score_correction_bias [256] f32
    float* out = (float*)d_out;                  // [16384*8 idx | 16384*8 weights] f32

    router_fused_f32<<<T_TOKENS / BT, 256, 0, stream>>>(hs, wt, bias, out);
}

// Round 4
// 627.471 us; speedup vs baseline: 1.4025x; 1.4025x over previous
//
#include <hip/hip_runtime.h>
#include <math.h>

#define T_TOKENS 16384
#define HID      4096
#define NEXP     256
#define NGROUP   8
#define GSIZE    32
#define TOPKG    4
#define TOPK     8
#define RSCALE   2.5f

#define TAU   5e-5f      // expert-score margin (score err sigma ~1.3e-6 -> ~38 sigma)
#define TAUG  1e-4f      // group-score margin

#define BM  64
#define BK  32
#define NK  (HID / BK)          // 128 K-steps

typedef __attribute__((ext_vector_type(8))) short bf16x8;
typedef __attribute__((ext_vector_type(4))) float f32x4;

// LDS staging bases (ushort units). Frag-major layout:
//   elem(r,k) = (r>>4)*512 + (k>>3)*128 + (r&15)*8 + (k&7)
// Frag read = base + tile*512 + lane*8 ushorts (lane-linear b128, conflict-free).
// A and B staged with the SAME (lane,elem)->k map => k-permutation cancels.
#define AHI 0
#define ALO 2048
#define BHI 4096
#define BLO 12288

// Split float4 into packed bf16 hi (RNE) and lo (RNE of exact residual).
__device__ __forceinline__ void split4(const float4 v, uint& h01, uint& h23,
                                       uint& l01, uint& l23) {
    const uint u0 = __float_as_uint(v.x) + 0x8000u;
    const uint u1 = __float_as_uint(v.y) + 0x8000u;
    const uint u2 = __float_as_uint(v.z) + 0x8000u;
    const uint u3 = __float_as_uint(v.w) + 0x8000u;
    h01 = __builtin_amdgcn_perm(u1, u0, 0x07060302u);   // lo16 = bf16(v.x), hi16 = bf16(v.y)
    h23 = __builtin_amdgcn_perm(u3, u2, 0x07060302u);
    const float f0 = v.x - __uint_as_float(u0 & 0xFFFF0000u);   // exact residual
    const float f1 = v.y - __uint_as_float(u1 & 0xFFFF0000u);
    const float f2 = v.z - __uint_as_float(u2 & 0xFFFF0000u);
    const float f3 = v.w - __uint_as_float(u3 & 0xFFFF0000u);
    l01 = __builtin_amdgcn_perm(__float_as_uint(f1) + 0x8000u,
                                __float_as_uint(f0) + 0x8000u, 0x07060302u);
    l23 = __builtin_amdgcn_perm(__float_as_uint(f3) + 0x8000u,
                                __float_as_uint(f2) + 0x8000u, 0x07060302u);
}

// ---- shared routing decision (identical logic in fast, cleanup, fallback paths) ----
// sc(e) -> sigmoid score of expert e.  Returns true if any decision margin is tight.
template <class SC>
__device__ __forceinline__ bool route_core(SC sc, const float* __restrict__ bias,
                                           int* id, float* wv)
{
    // group scores: sum of top-2 of (score + bias) per group of 32
    float gs[NGROUP];
#pragma unroll
    for (int g = 0; g < NGROUP; ++g) {
        float m1 = -1e30f, m2 = -1e30f;
        for (int i = 0; i < GSIZE; ++i) {
            const int e = g * GSIZE + i;
            const float v = sc(e) + bias[e];
            if (v > m1)      { m2 = m1; m1 = v; }
            else if (v > m2) { m2 = v; }
        }
        gs[g] = m1 + m2;
    }

    // top-4 groups (strict >, lower index wins ties — matches lax.top_k)
    unsigned gmask = 0;
    float g4 = -1e30f;
#pragma unroll
    for (int r = 0; r < TOPKG; ++r) {
        int bi = 0; float bv = -1e30f;
#pragma unroll
        for (int g = 0; g < NGROUP; ++g) {
            const bool taken = (gmask >> g) & 1;
            if (!taken && gs[g] > bv) { bv = gs[g]; bi = g; }
        }
        gmask |= 1u << bi;
        g4 = bv;                                     // 4th pick = min of selected
    }
    float g5 = -1e30f;                               // best rejected group
#pragma unroll
    for (int g = 0; g < NGROUP; ++g)
        if (!((gmask >> g) & 1) && gs[g] > g5) g5 = gs[g];

    // top-9 over masked array (disallowed -> exact 0.0, like reference);
    // stable insertion (strict >) keeps lower-index-first tie order
    float val[TOPK + 1]; int vid[TOPK + 1];
#pragma unroll
    for (int r = 0; r <= TOPK; ++r) { val[r] = -1e30f; vid[r] = 0; }
    for (int e = 0; e < NEXP; ++e) {
        const bool allowed = (gmask >> (e >> 5)) & 1;
        const float v = allowed ? (sc(e) + bias[e]) : 0.0f;
        if (v > val[TOPK]) {
#pragma unroll
            for (int p = TOPK; p >= 1; --p) {
                if (v > val[p - 1])  { val[p] = val[p - 1]; vid[p] = vid[p - 1]; }
                else if (v > val[p]) { val[p] = v;          vid[p] = e; }
            }
            if (v > val[0]) { val[0] = v; vid[0] = e; }
        }
    }

    // margins: group boundary + all adjacent expert gaps incl. 8th-vs-9th
    bool tight = (g4 - g5 < TAUG);
#pragma unroll
    for (int i = 0; i < TOPK; ++i) tight |= (val[i] - val[i + 1] < TAU);

    // weights: pure sigmoid scores at chosen indices, normalized, scaled
    float sum = 0.0f;
#pragma unroll
    for (int r = 0; r < TOPK; ++r) { id[r] = vid[r]; wv[r] = sc(vid[r]); sum += wv[r]; }
    const float inv = RSCALE / (sum + 1e-20f);
#pragma unroll
    for (int r = 0; r < TOPK; ++r) wv[r] *= inv;
    return tight;
}

// exact fp32 recompute + route for one token (cold fallback; scratch-heavy is fine)
__device__ void exact_token(const float* __restrict__ hs, const float* __restrict__ wt,
                            const float* __restrict__ bias, float* __restrict__ out, int t)
{
    float lg[NEXP];
    const float* hrow = hs + (size_t)t * HID;
    for (int e = 0; e < NEXP; ++e) {
        const float* wr = wt + (size_t)e * HID;
        float a = 0.0f;
        for (int k = 0; k < HID; k += 4) {
            const float4 x = *(const float4*)(hrow + k);
            const float4 b = *(const float4*)(wr + k);
            a = fmaf(x.x, b.x, a); a = fmaf(x.y, b.y, a);
            a = fmaf(x.z, b.z, a); a = fmaf(x.w, b.w, a);
        }
        lg[e] = 1.0f / (1.0f + expf(-a));
    }
    int id[TOPK]; float wv[TOPK];
    route_core([&](int e) { return lg[e]; }, bias, id, wv);
    for (int r = 0; r < TOPK; ++r) {
        out[(size_t)t * TOPK + r] = (float)id[r];
        out[(size_t)T_TOKENS * TOPK + (size_t)t * TOPK + r] = wv[r];
    }
}

__global__ __launch_bounds__(256, 1)
void router_mfma(const float* __restrict__ hs,
                 const float* __restrict__ wt,
                 const float* __restrict__ bias,
                 float* __restrict__ out,
                 unsigned* __restrict__ wcnt,       // may be null
                 unsigned* __restrict__ wlist,
                 unsigned cap)
{
    // 64 KB: staging (40 KB) during GEMM, then Lg[256 experts][64 tokens] (swizzled)
    __shared__ float smem[16384];
    ushort* u16 = (ushort*)smem;
    float*  Lg  = smem;

    const int tid  = threadIdx.x;
    const int lane = tid & 63;
    const int w    = tid >> 6;        // wave -> expert cols w*64..w*64+63
    const int t0   = blockIdx.x * BM;

    const int gr = tid >> 3;          // staging row-in-group 0..31
    const int gq = tid & 7;           // staging float4 index 0..7

    f32x4 acc[4][4];
#pragma unroll
    for (int i = 0; i < 4; ++i)
#pragma unroll
        for (int j = 0; j < 4; ++j) acc[i][j] = (f32x4)0.0f;

    float4 ra[2], rb[8];
#pragma unroll
    for (int s = 0; s < 2; ++s)
        ra[s] = *(const float4*)(hs + (size_t)(t0 + gr + s * 32) * HID + gq * 4);
#pragma unroll
    for (int s = 0; s < 8; ++s)
        rb[s] = *(const float4*)(wt + (size_t)(gr + s * 32) * HID + gq * 4);

    for (int ks = 0; ks < NK; ++ks) {
        __syncthreads();   // previous compute done; LDS reusable

        // ---- convert regs -> bf16 hi/lo, write frag-major LDS ----
#pragma unroll
        for (int s = 0; s < 2; ++s) {
            const int r = gr + s * 32;
            uint h01, h23, l01, l23;
            split4(ra[s], h01, h23, l01, l23);
            const int eo = (r >> 4) * 512 + (gq >> 1) * 128 + (r & 15) * 8 + (gq & 1) * 4;
            uint2 hv; hv.x = h01; hv.y = h23;
            uint2 lv; lv.x = l01; lv.y = l23;
            *(uint2*)&u16[AHI + eo] = hv;
            *(uint2*)&u16[ALO + eo] = lv;
        }
#pragma unroll
        for (int s = 0; s < 8; ++s) {
            const int e = gr + s * 32;
            uint h01, h23, l01, l23;
            split4(rb[s], h01, h23, l01, l23);
            const int eo = (e >> 4) * 512 + (gq >> 1) * 128 + (e & 15) * 8 + (gq & 1) * 4;
            uint2 hv; hv.x = h01; hv.y = h23;
            uint2 lv; lv.x = l01; lv.y = l23;
            *(uint2*)&u16[BHI + eo] = hv;
            *(uint2*)&u16[BLO + eo] = lv;
        }
        __syncthreads();

        // ---- prefetch next K-step into regs ----
        if (ks + 1 < NK) {
            const int k0 = (ks + 1) * BK;
#pragma unroll
            for (int s = 0; s < 2; ++s)
                ra[s] = *(const float4*)(hs + (size_t)(t0 + gr + s * 32) * HID + k0 + gq * 4);
#pragma unroll
            for (int s = 0; s < 8; ++s)
                rb[s] = *(const float4*)(wt + (size_t)(gr + s * 32) * HID + k0 + gq * 4);
        }

        // ---- compute: lane-linear b128 frag reads + 48 MFMA ----
        bf16x8 ah[4], al[4];
#pragma unroll
        for (int rt = 0; rt < 4; ++rt) {
            ah[rt] = *(const bf16x8*)&u16[AHI + rt * 512 + lane * 8];
            al[rt] = *(const bf16x8*)&u16[ALO + rt * 512 + lane * 8];
        }
#pragma unroll
        for (int c = 0; c < 4; ++c) {
            const int ct = w * 4 + c;
            const bf16x8 bh = *(const bf16x8*)&u16[BHI + ct * 512 + lane * 8];
            const bf16x8 bl = *(const bf16x8*)&u16[BLO + ct * 512 + lane * 8];
#pragma unroll
            for (int rt = 0; rt < 4; ++rt) {
                acc[rt][c] = __builtin_amdgcn_mfma_f32_16x16x32_bf16(ah[rt], bh, acc[rt][c], 0, 0, 0);
                acc[rt][c] = __builtin_amdgcn_mfma_f32_16x16x32_bf16(ah[rt], bl, acc[rt][c], 0, 0, 0);
                acc[rt][c] = __builtin_amdgcn_mfma_f32_16x16x32_bf16(al[rt], bh, acc[rt][c], 0, 0, 0);
            }
        }
    }

    __syncthreads();   // staging dead -> reuse as Lg

    // ---- sigmoid -> Lg[expert][token] (add-swizzle), HW-confirmed C/D mapping ----
#pragma unroll
    for (int rt = 0; rt < 4; ++rt)
#pragma unroll
        for (int c = 0; c < 4; ++c) {
            const int col  = w * 64 + c * 16 + (lane & 15);          // expert
            const int rowb = rt * 16 + (lane >> 4) * 4;              // token base
#pragma unroll
            for (int j = 0; j < 4; ++j) {
                const int row = rowb + j;
                const float x = acc[rt][c][j];
                Lg[col * 64 + ((row + col) & 63)] = 1.0f / (1.0f + expf(-x));
            }
        }
    __syncthreads();

    // ---- routing: one thread per token ----
    if (tid < BM) {
        const int t = t0 + tid;
        int id[TOPK]; float wv[TOPK];
        const bool tight = route_core(
            [&](int e) { return Lg[e * 64 + ((tid + e) & 63)]; }, bias, id, wv);

#pragma unroll
        for (int r = 0; r < TOPK; ++r) {
            out[(size_t)t * TOPK + r] = (float)id[r];
            out[(size_t)T_TOKENS * TOPK + (size_t)t * TOPK + r] = wv[r];
        }

        if (tight) {
            bool queued = false;
            if (wcnt) {
                const unsigned pos = atomicAdd(wcnt, 1u);
                if (pos < cap) { wlist[pos] = (unsigned)t; queued = true; }
            }
            if (!queued) exact_token(hs, wt, bias, out, t);   // cold fallback
        }
    }
}

// cleanup: exact fp32 recompute of flagged tokens, 2 tokens per block-pass
__global__ __launch_bounds__(256, 4)
void router_exact(const float* __restrict__ hs,
                  const float* __restrict__ wt,
                  const float* __restrict__ bias,
                  float* __restrict__ out,
                  const unsigned* __restrict__ wcnt,
                  const unsigned* __restrict__ wlist,
                  unsigned cap)
{
    __shared__ float lg[2][NEXP];
    __shared__ int   toks[2];
    const unsigned count = min(*wcnt, cap);
    const int tid = threadIdx.x;

    for (unsigned base = blockIdx.x * 2; base < count; base += gridDim.x * 2) {
        const int n = (base + 1 < count) ? 2 : 1;
        if (tid < n) toks[tid] = (int)wlist[base + tid];
        __syncthreads();

        const int ta = toks[0];
        const int tb = (n == 2) ? toks[1] : toks[0];
        const float* h0 = hs + (size_t)ta * HID;
        const float* h1 = hs + (size_t)tb * HID;
        const float* wr = wt + (size_t)tid * HID;     // thread = expert
        float a0 = 0.0f, a1 = 0.0f;
        for (int k = 0; k < HID; k += 4) {
            const float4 b  = *(const float4*)(wr + k);
            const float4 x0 = *(const float4*)(h0 + k);
            const float4 x1 = *(const float4*)(h1 + k);
            a0 = fmaf(x0.x, b.x, a0); a0 = fmaf(x0.y, b.y, a0);
            a0 = fmaf(x0.z, b.z, a0); a0 = fmaf(x0.w, b.w, a0);
            a1 = fmaf(x1.x, b.x, a1); a1 = fmaf(x1.y, b.y, a1);
            a1 = fmaf(x1.z, b.z, a1); a1 = fmaf(x1.w, b.w, a1);
        }
        lg[0][tid] = 1.0f / (1.0f + expf(-a0));
        lg[1][tid] = 1.0f / (1.0f + expf(-a1));
        __syncthreads();

        if (tid < n) {
            const int t = toks[tid];
            int id[TOPK]; float wv[TOPK];
            route_core([&](int e) { return lg[tid][e]; }, bias, id, wv);
            for (int r = 0; r < TOPK; ++r) {
                out[(size_t)t * TOPK + r] = (float)id[r];
                out[(size_t)T_TOKENS * TOPK + (size_t)t * TOPK + r] = wv[r];
            }
        }
        // loop-top __syncthreads orders toks/lg reuse
    }
}

extern "C" void kernel_launch(void* const* d_in, const int* in_sizes, int n_in,
                              void* d_out, int out_size, void* d_ws, size_t ws_size,
                              hipStream_t stream) {
    const float* hs   = (const float*)d_in[0];   // [16384, 4096] f32
    const float* wt   = (const float*)d_in[1];   // [256, 4096]   f32
    const float* bias = (const float*)d_in[2];   // [256]         f32
    float* out = (float*)d_out;
    (void)in_sizes; (void)n_in; (void)out_size;

    unsigned cap = 0;
    unsigned* wcnt = nullptr;
    unsigned* wlist = nullptr;
    if (ws_size >= 8) {
        cap = (unsigned)((ws_size - 4) / 4);
        if (cap > T_TOKENS) cap = T_TOKENS;
        wcnt  = (unsigned*)d_ws;
        wlist = wcnt + 1;
        hipMemsetAsync(d_ws, 0, sizeof(unsigned), stream);   // zero worklist counter
    }

    router_mfma<<<T_TOKENS / BM, 256, 0, stream>>>(hs, wt, bias, out, wcnt, wlist, cap);
    if (cap > 0)
        router_exact<<<128, 256, 0, stream>>>(hs, wt, bias, out, wcnt, wlist, cap);
}

// Round 5
// 551.726 us; speedup vs baseline: 1.5950x; 1.1373x over previous
//
#include <hip/hip_runtime.h>
#include <math.h>

#define T_TOKENS 16384
#define HID      4096
#define NEXP     256
#define NGROUP   8
#define GSIZE    32
#define TOPKG    4
#define TOPK     8
#define RSCALE   2.5f

#define TAU   2e-5f      // expert-score margin (score err sigma ~1.7e-6 -> ~12 sigma)
#define TAUG  3e-5f      // group-score margin

#define BM  64
#define BK  32
#define NK  (HID / BK)          // 128 K-steps

typedef __attribute__((ext_vector_type(8))) short bf16x8;
typedef __attribute__((ext_vector_type(4))) float f32x4;

// LDS staging bases (ushort units). Frag-major layout:
//   elem(r,k) = (r>>4)*512 + (k>>3)*128 + (r&15)*8 + (k&7)
// Frag read = base + tile*512 + lane*8 ushorts (lane-linear b128, conflict-free).
// A and B staged with the SAME (lane,elem)->k map => k-permutation cancels.
#define AHI 0
#define ALO 2048
#define BHI 4096
#define BLO 12288

// Split float4 into packed bf16 hi (RNE) and lo (RNE of exact residual).
__device__ __forceinline__ void split4(const float4 v, uint& h01, uint& h23,
                                       uint& l01, uint& l23) {
    const uint u0 = __float_as_uint(v.x) + 0x8000u;
    const uint u1 = __float_as_uint(v.y) + 0x8000u;
    const uint u2 = __float_as_uint(v.z) + 0x8000u;
    const uint u3 = __float_as_uint(v.w) + 0x8000u;
    h01 = __builtin_amdgcn_perm(u1, u0, 0x07060302u);   // lo16 = bf16(v.x), hi16 = bf16(v.y)
    h23 = __builtin_amdgcn_perm(u3, u2, 0x07060302u);
    const float f0 = v.x - __uint_as_float(u0 & 0xFFFF0000u);   // exact residual
    const float f1 = v.y - __uint_as_float(u1 & 0xFFFF0000u);
    const float f2 = v.z - __uint_as_float(u2 & 0xFFFF0000u);
    const float f3 = v.w - __uint_as_float(u3 & 0xFFFF0000u);
    l01 = __builtin_amdgcn_perm(__float_as_uint(f1) + 0x8000u,
                                __float_as_uint(f0) + 0x8000u, 0x07060302u);
    l23 = __builtin_amdgcn_perm(__float_as_uint(f3) + 0x8000u,
                                __float_as_uint(f2) + 0x8000u, 0x07060302u);
}

// ---- shared routing decision (identical logic in all paths) ----
template <class SC>
__device__ __forceinline__ bool route_core(SC sc, const float* __restrict__ bias,
                                           int* id, float* wv)
{
    // group scores: sum of top-2 of (score + bias) per group of 32
    float gs[NGROUP];
#pragma unroll
    for (int g = 0; g < NGROUP; ++g) {
        float m1 = -1e30f, m2 = -1e30f;
        for (int i = 0; i < GSIZE; ++i) {
            const int e = g * GSIZE + i;
            const float v = sc(e) + bias[e];
            if (v > m1)      { m2 = m1; m1 = v; }
            else if (v > m2) { m2 = v; }
        }
        gs[g] = m1 + m2;
    }

    // top-4 groups (strict >, lower index wins ties — matches lax.top_k)
    unsigned gmask = 0;
    float g4 = -1e30f;
#pragma unroll
    for (int r = 0; r < TOPKG; ++r) {
        int bi = 0; float bv = -1e30f;
#pragma unroll
        for (int g = 0; g < NGROUP; ++g) {
            const bool taken = (gmask >> g) & 1;
            if (!taken && gs[g] > bv) { bv = gs[g]; bi = g; }
        }
        gmask |= 1u << bi;
        g4 = bv;                                     // 4th pick = min of selected
    }
    float g5 = -1e30f;                               // best rejected group
#pragma unroll
    for (int g = 0; g < NGROUP; ++g)
        if (!((gmask >> g) & 1) && gs[g] > g5) g5 = gs[g];

    // top-9 over masked array (disallowed -> exact 0.0, like reference);
    // stable insertion (strict >) keeps lower-index-first tie order
    float val[TOPK + 1]; int vid[TOPK + 1];
#pragma unroll
    for (int r = 0; r <= TOPK; ++r) { val[r] = -1e30f; vid[r] = 0; }
    for (int e = 0; e < NEXP; ++e) {
        const bool allowed = (gmask >> (e >> 5)) & 1;
        const float v = allowed ? (sc(e) + bias[e]) : 0.0f;
        if (v > val[TOPK]) {
#pragma unroll
            for (int p = TOPK; p >= 1; --p) {
                if (v > val[p - 1])  { val[p] = val[p - 1]; vid[p] = vid[p - 1]; }
                else if (v > val[p]) { val[p] = v;          vid[p] = e; }
            }
            if (v > val[0]) { val[0] = v; vid[0] = e; }
        }
    }

    // margins: group boundary + all adjacent expert gaps incl. 8th-vs-9th
    bool tight = (g4 - g5 < TAUG);
#pragma unroll
    for (int i = 0; i < TOPK; ++i) tight |= (val[i] - val[i + 1] < TAU);

    // weights: pure sigmoid scores at chosen indices, normalized, scaled
    float sum = 0.0f;
#pragma unroll
    for (int r = 0; r < TOPK; ++r) { id[r] = vid[r]; wv[r] = sc(vid[r]); sum += wv[r]; }
    const float inv = RSCALE / (sum + 1e-20f);
#pragma unroll
    for (int r = 0; r < TOPK; ++r) wv[r] *= inv;
    return tight;
}

// exact fp32 recompute + route for one token (cold fallback only)
__device__ void exact_token(const float* __restrict__ hs, const float* __restrict__ wt,
                            const float* __restrict__ bias, float* __restrict__ out, int t)
{
    float lg[NEXP];
    const float* hrow = hs + (size_t)t * HID;
    for (int e = 0; e < NEXP; ++e) {
        const float* wr = wt + (size_t)e * HID;
        float a = 0.0f;
        for (int k = 0; k < HID; k += 4) {
            const float4 x = *(const float4*)(hrow + k);
            const float4 b = *(const float4*)(wr + k);
            a = fmaf(x.x, b.x, a); a = fmaf(x.y, b.y, a);
            a = fmaf(x.z, b.z, a); a = fmaf(x.w, b.w, a);
        }
        lg[e] = 1.0f / (1.0f + expf(-a));
    }
    int id[TOPK]; float wv[TOPK];
    route_core([&](int e) { return lg[e]; }, bias, id, wv);
    for (int r = 0; r < TOPK; ++r) {
        out[(size_t)t * TOPK + r] = (float)id[r];
        out[(size_t)T_TOKENS * TOPK + (size_t)t * TOPK + r] = wv[r];
    }
}

// 512 threads = 8 waves (2/SIMD). Wave w owns experts w*32..w*32+31.
__global__ __launch_bounds__(512, 1)
void router_mfma(const float* __restrict__ hs,
                 const float* __restrict__ wt,
                 const float* __restrict__ bias,
                 float* __restrict__ out,
                 unsigned* __restrict__ wcnt,       // may be null
                 unsigned* __restrict__ wlist,
                 unsigned cap)
{
    // 64 KB: staging (40 KB) during GEMM, then Lg[256 experts][64 tokens] (swizzled)
    __shared__ float smem[16384];
    ushort* u16 = (ushort*)smem;
    float*  Lg  = smem;

    const int tid  = threadIdx.x;
    const int lane = tid & 63;
    const int w    = tid >> 6;        // wave 0..7 -> experts w*32..w*32+31
    const int t0   = blockIdx.x * BM;

    const int ar = tid >> 3;          // staging row 0..63
    const int aq = tid & 7;           // staging float4 index 0..7

    f32x4 acc[4][2];
#pragma unroll
    for (int i = 0; i < 4; ++i)
#pragma unroll
        for (int j = 0; j < 2; ++j) acc[i][j] = (f32x4)0.0f;

    float4 ra, rb[4];
    ra = *(const float4*)(hs + (size_t)(t0 + ar) * HID + aq * 4);
#pragma unroll
    for (int s = 0; s < 4; ++s)
        rb[s] = *(const float4*)(wt + (size_t)(ar + s * 64) * HID + aq * 4);

    for (int ks = 0; ks < NK; ++ks) {
        __syncthreads();   // previous compute done; LDS reusable

        // ---- convert regs -> bf16 hi/lo, write frag-major LDS ----
        {
            uint h01, h23, l01, l23;
            split4(ra, h01, h23, l01, l23);
            const int eo = (ar >> 4) * 512 + (aq >> 1) * 128 + (ar & 15) * 8 + (aq & 1) * 4;
            uint2 hv; hv.x = h01; hv.y = h23;
            uint2 lv; lv.x = l01; lv.y = l23;
            *(uint2*)&u16[AHI + eo] = hv;
            *(uint2*)&u16[ALO + eo] = lv;
        }
#pragma unroll
        for (int s = 0; s < 4; ++s) {
            const int e = ar + s * 64;
            uint h01, h23, l01, l23;
            split4(rb[s], h01, h23, l01, l23);
            const int eo = (e >> 4) * 512 + (aq >> 1) * 128 + (e & 15) * 8 + (aq & 1) * 4;
            uint2 hv; hv.x = h01; hv.y = h23;
            uint2 lv; lv.x = l01; lv.y = l23;
            *(uint2*)&u16[BHI + eo] = hv;
            *(uint2*)&u16[BLO + eo] = lv;
        }
        __syncthreads();

        // ---- prefetch next K-step into regs (latency hides under MFMA + other wave) ----
        if (ks + 1 < NK) {
            const int k0 = (ks + 1) * BK;
            ra = *(const float4*)(hs + (size_t)(t0 + ar) * HID + k0 + aq * 4);
#pragma unroll
            for (int s = 0; s < 4; ++s)
                rb[s] = *(const float4*)(wt + (size_t)(ar + s * 64) * HID + k0 + aq * 4);
        }

        // ---- compute: lane-linear b128 frag reads + 24 MFMA/wave ----
        bf16x8 ah[4], al[4];
#pragma unroll
        for (int rt = 0; rt < 4; ++rt) {
            ah[rt] = *(const bf16x8*)&u16[AHI + rt * 512 + lane * 8];
            al[rt] = *(const bf16x8*)&u16[ALO + rt * 512 + lane * 8];
        }
#pragma unroll
        for (int c = 0; c < 2; ++c) {
            const int ct = w * 2 + c;
            const bf16x8 bh = *(const bf16x8*)&u16[BHI + ct * 512 + lane * 8];
            const bf16x8 bl = *(const bf16x8*)&u16[BLO + ct * 512 + lane * 8];
#pragma unroll
            for (int rt = 0; rt < 4; ++rt) {
                acc[rt][c] = __builtin_amdgcn_mfma_f32_16x16x32_bf16(ah[rt], bh, acc[rt][c], 0, 0, 0);
                acc[rt][c] = __builtin_amdgcn_mfma_f32_16x16x32_bf16(ah[rt], bl, acc[rt][c], 0, 0, 0);
                acc[rt][c] = __builtin_amdgcn_mfma_f32_16x16x32_bf16(al[rt], bh, acc[rt][c], 0, 0, 0);
            }
        }
    }

    __syncthreads();   // staging dead -> reuse as Lg

    // ---- sigmoid -> Lg[expert][token] (add-swizzle), HW-confirmed C/D mapping ----
#pragma unroll
    for (int rt = 0; rt < 4; ++rt)
#pragma unroll
        for (int c = 0; c < 2; ++c) {
            const int col  = w * 32 + c * 16 + (lane & 15);          // expert
            const int rowb = rt * 16 + (lane >> 4) * 4;              // token base
#pragma unroll
            for (int j = 0; j < 4; ++j) {
                const int row = rowb + j;
                const float x = acc[rt][c][j];
                Lg[col * 64 + ((row + col) & 63)] = 1.0f / (1.0f + expf(-x));
            }
        }
    __syncthreads();

    // ---- routing: one thread per token (threads 0..63) ----
    if (tid < BM) {
        const int t = t0 + tid;
        int id[TOPK]; float wv[TOPK];
        const bool tight = route_core(
            [&](int e) { return Lg[e * 64 + ((tid + e) & 63)]; }, bias, id, wv);

#pragma unroll
        for (int r = 0; r < TOPK; ++r) {
            out[(size_t)t * TOPK + r] = (float)id[r];
            out[(size_t)T_TOKENS * TOPK + (size_t)t * TOPK + r] = wv[r];
        }

        if (tight) {
            bool queued = false;
            if (wcnt) {
                const unsigned pos = atomicAdd(wcnt, 1u);
                if (pos < cap) { wlist[pos] = (unsigned)t; queued = true; }
            }
            if (!queued) exact_token(hs, wt, bias, out, t);   // cold fallback
        }
    }
}

// cleanup: exact fp32 recompute of flagged tokens, 4 tokens per block-pass
__global__ __launch_bounds__(256, 2)
void router_exact(const float* __restrict__ hs,
                  const float* __restrict__ wt,
                  const float* __restrict__ bias,
                  float* __restrict__ out,
                  const unsigned* __restrict__ wcnt,
                  const unsigned* __restrict__ wlist,
                  unsigned cap)
{
    __shared__ float lg[4][NEXP + 1];     // +1 pad: routing scan de-conflict
    __shared__ int   toks[4];
    const unsigned count = min(*wcnt, cap);
    const int tid = threadIdx.x;

    for (unsigned base = blockIdx.x * 4u; base < count; base += gridDim.x * 4u) {
        const unsigned n = min(4u, count - base);
        __syncthreads();                               // protect prev-iter lg/toks reads
        if (tid < 4) toks[tid] = (int)wlist[base + min((unsigned)tid, n - 1)];
        __syncthreads();

        const float* wr = wt + (size_t)tid * HID;      // thread = expert
        const float* hp[4];
#pragma unroll
        for (int j = 0; j < 4; ++j) hp[j] = hs + (size_t)toks[j] * HID;

        float a[4] = {0.0f, 0.0f, 0.0f, 0.0f};
        for (int k = 0; k < HID; k += 4) {
            const float4 b = *(const float4*)(wr + k);
#pragma unroll
            for (int j = 0; j < 4; ++j) {
                const float4 x = *(const float4*)(hp[j] + k);
                a[j] = fmaf(x.x, b.x, a[j]); a[j] = fmaf(x.y, b.y, a[j]);
                a[j] = fmaf(x.z, b.z, a[j]); a[j] = fmaf(x.w, b.w, a[j]);
            }
        }
#pragma unroll
        for (int j = 0; j < 4; ++j) lg[j][tid] = 1.0f / (1.0f + expf(-a[j]));
        __syncthreads();

        if (tid < (int)n) {
            const int t = toks[tid];
            int id[TOPK]; float wv[TOPK];
            route_core([&](int e) { return lg[tid][e]; }, bias, id, wv);
            for (int r = 0; r < TOPK; ++r) {
                out[(size_t)t * TOPK + r] = (float)id[r];
                out[(size_t)T_TOKENS * TOPK + (size_t)t * TOPK + r] = wv[r];
            }
        }
    }
}

extern "C" void kernel_launch(void* const* d_in, const int* in_sizes, int n_in,
                              void* d_out, int out_size, void* d_ws, size_t ws_size,
                              hipStream_t stream) {
    const float* hs   = (const float*)d_in[0];   // [16384, 4096] f32
    const float* wt   = (const float*)d_in[1];   // [256, 4096]   f32
    const float* bias = (const float*)d_in[2];   // [256]         f32
    float* out = (float*)d_out;
    (void)in_sizes; (void)n_in; (void)out_size;

    unsigned cap = 0;
    unsigned* wcnt = nullptr;
    unsigned* wlist = nullptr;
    if (ws_size >= 8) {
        cap = (unsigned)((ws_size - 4) / 4);
        if (cap > T_TOKENS) cap = T_TOKENS;
        wcnt  = (unsigned*)d_ws;
        wlist = wcnt + 1;
        hipMemsetAsync(d_ws, 0, sizeof(unsigned), stream);   // zero worklist counter
    }

    router_mfma<<<T_TOKENS / BM, 512, 0, stream>>>(hs, wt, bias, out, wcnt, wlist, cap);
    if (cap > 0)
        router_exact<<<256, 256, 0, stream>>>(hs, wt, bias, out, wcnt, wlist, cap);
}